// Round 5
// baseline (280.955 us; speedup 1.0000x reference)
//
#include <hip/hip_runtime.h>
#include <math.h>

#define BATCH 256

typedef __attribute__((ext_vector_type(8))) short bf16x8;
typedef __attribute__((ext_vector_type(16))) float f32x16;

__device__ __forceinline__ float wave_reduce_sum(float v) {
    #pragma unroll
    for (int off = 32; off > 0; off >>= 1) v += __shfl_down(v, off, 64);
    return v;
}

__device__ __forceinline__ unsigned short f2bf(float f) {
    unsigned u = __float_as_uint(f);
    u += 0x7FFF + ((u >> 16) & 1);      // round-to-nearest-even
    return (unsigned short)(u >> 16);
}

// Fast tanh + log(1-tanh^2) from one exp:
//   u = e^(-2|v|); t = sgn(v)*(1-u)/(1+u); log(1-t^2) = log4 - 2|v| - 2*log(1+u)
__device__ __forceinline__ float fast_tanh_ld(float v, float& lsum) {
    float av = fabsf(v);
    float u = __expf(-2.0f * av);
    float onep = 1.0f + u;
    float rin = __builtin_amdgcn_rcpf(onep);
    lsum += 1.3862943611f - 2.0f * av - 2.0f * __logf(onep);
    return copysignf((1.0f - u) * rin, v);
}

__global__ __launch_bounds__(256) void init_kernel(float* acc, float* consts) {
    int t = threadIdx.x;
    acc[t] = 0.0f;
    if (t == 0) consts[0] = 0.0f;
}

// Parallel closed-form (Parseval) spectral logdet + actnorm logdet.
__global__ __launch_bounds__(256) void logdet_const_kernel(
        const float* __restrict__ K0, const float* __restrict__ als0,
        const float* __restrict__ K1, const float* __restrict__ als1,
        const float* __restrict__ K2, const float* __restrict__ als2,
        float* consts) {
    const int g = blockIdx.x * 256 + threadIdx.x;
    float val = 0.0f;
    if (g < 39312) {
        const float* K; int c, nn, ij;
        if (g < 144)       { K = K0; c = 12;  nn = 4096; ij = g; }
        else if (g < 2448) { K = K1; c = 48;  nn = 1024; ij = g - 144; }
        else               { K = K2; c = 192; nn = 256;  ij = g - 2448; }
        const int i = ij / c, j = ij - (ij / c) * c;
        const float* a  = K + (size_t)(i * c + j) * 9;
        const float* bp = K + (size_t)(j * c + i) * 9;
        float s = 0.0f;
        #pragma unroll
        for (int p = 0; p < 9; ++p) {
            const bool sub = (i == j) && (p == 4);
            float av = a[p]      - (sub ? 1.0f : 0.0f);
            float bv = bp[8 - p] - (sub ? 1.0f : 0.0f);
            s = fmaf(av, bv, s);
        }
        val = ((i == j) ? (a[4] - 1.0f) : 0.0f) - 0.5f * s;
        val *= (float)nn;
    } else if (g < 39564) {
        const int g2 = g - 39312;
        if (g2 < 12)      val = als0[g2] * 4096.0f;
        else if (g2 < 60) val = als1[g2 - 12] * 1024.0f;
        else              val = als2[g2 - 60] * 256.0f;
    }
    val = wave_reduce_sum(val);
    __shared__ float red[4];
    const int tid = threadIdx.x;
    if ((tid & 63) == 0) red[tid >> 6] = val;
    __syncthreads();
    if (tid == 0) atomicAdd(consts, red[0] + red[1] + red[2] + red[3]);
}

// Fragment-packed weights (A-operand layout: m=lane&31, k=(lane>>5)*8+e) and
// prebaked exp(als) table: esc[0..12)=l0, [12..60)=l1, [60..252)=l2.
// W2p is packed kt-MAJOR: (12 kt, 9 tap, 6 cog, 64 lane, 8 e) so that one
// kt-slice (27648 elems = 55296 B) is contiguous for LDS staging in conv2.
__global__ __launch_bounds__(256) void prep_weights(
        const float* __restrict__ K0, const float* __restrict__ K1,
        const float* __restrict__ K2,
        const float* __restrict__ als0, const float* __restrict__ als1,
        const float* __restrict__ als2,
        unsigned short* __restrict__ W0p, unsigned short* __restrict__ W1p,
        unsigned short* __restrict__ W2p, float* __restrict__ esc) {
    const int i = blockIdx.x * 256 + threadIdx.x;
    if (i < 252) {
        if (i < 12)      esc[i] = expf(als0[i]);
        else if (i < 60) esc[i] = expf(als1[i - 12]);
        else             esc[i] = expf(als2[i - 60]);
    }
    if (i < 4608) {                // 9 taps * 512
        int t = i;
        const int e  = t & 7;  t >>= 3;
        const int ln = t & 31; t >>= 5;
        const int kg = t & 1;  t >>= 1;
        const int tap = t;
        const int co = ln, ci = kg * 8 + e;
        W0p[i] = (co < 12 && ci < 12) ? f2bf(K0[((size_t)co * 12 + ci) * 9 + tap])
                                      : (unsigned short)0;
    }
    if (i < 27648) {               // 9 taps * 2 cog * 3 kt * 512
        int t = i;
        const int e  = t & 7;  t >>= 3;
        const int ln = t & 31; t >>= 5;
        const int kg = t & 1;  t >>= 1;
        const int kt = t % 3;  t /= 3;
        const int cog = t & 1; const int tap = t >> 1;
        const int co = cog * 32 + ln, ci = kt * 16 + kg * 8 + e;
        W1p[i] = (co < 48) ? f2bf(K1[((size_t)co * 48 + ci) * 9 + tap]) : (unsigned short)0;
    }
    if (i < 331776) {              // 12 kt * 9 tap * 6 cog * 64 lane * 8 e
        int t = i;
        const int e    = t & 7;  t >>= 3;
        const int lane = t & 63; t >>= 6;
        const int cog  = t % 6;  t /= 6;
        const int tap  = t % 9;  const int kt = t / 9;
        const int ln = lane & 31, kg = lane >> 5;
        const int co = cog * 32 + ln, ci = kt * 16 + kg * 8 + e;
        W2p[i] = f2bf(K2[((size_t)co * 192 + ci) * 9 + tap]);
    }
}

// Layer 0, fused squeeze + conv. 4 blocks per batch (16 px-rows each), 256
// threads = 4 waves. LDS: 18-row squeezed slice (36.9 KB); W0 in registers.
// Epilogue: tanh results are scattered into LDS (input slice is dead after
// the MFMAs) in the exact X1 fragment layout, then copied out with coalesced
// 16B stores -- avoids the 2B-scattered global-store address-issue bottleneck.
__global__ __launch_bounds__(256, 3) void conv0_fused(
        const float* __restrict__ xin,          // (B,3,128,128) fp32
        const unsigned short* __restrict__ W0,  // packed (9,64,8)
        const float* __restrict__ cb,           // (12,64,64)
        const float* __restrict__ ab,           // (12)
        const float* __restrict__ esc,          // exp(als0) (12)
        unsigned short* __restrict__ X1,        // (B,6,1024,8) bf16
        float* __restrict__ logacc)             // (B)
{
    __shared__ __align__(16) char lds[36864];    // [18 slots][64 w][16 sh]
    unsigned short* Xsl = (unsigned short*)lds;
    __shared__ float red[4];

    const int tid = threadIdx.x;
    const int lane = tid & 63, wave = tid >> 6;
    const int ln = lane & 31, kg = lane >> 5;
    const int blk = blockIdx.x;
    const int b = blk >> 2, R0 = (blk & 3) << 4;

    // ---- weights -> registers (9 frags, 36 VGPR) ----
    const char* Wc = (const char*)W0 + (size_t)lane * 16;
    bf16x8 wreg[9];
    #pragma unroll
    for (int tap = 0; tap < 9; ++tap)
        wreg[tap] = *(const bf16x8*)(Wc + tap * 1024);

    // ---- fused squeeze of the 18-row slice ----
    {
        const float* base = xin + (size_t)b * 49152;
        #pragma unroll
        for (int rr = 0; rr < 5; ++rr) {
            const int s = rr * 256 + tid;
            if (s < 1152) {
                const int srow = s >> 6, w = s & 63;
                const int hr = (R0 - 1 + srow + 64) & 63;
                unsigned short vals[12];
                #pragma unroll
                for (int ci = 0; ci < 3; ++ci) {
                    #pragma unroll
                    for (int a = 0; a < 2; ++a) {
                        float2 v = *(const float2*)(base + ci * 16384 + (2 * hr + a) * 128 + 2 * w);
                        const int s0 = a ? 9 + ci : ci;
                        const int s1 = a ? 3 + ci : 6 + ci;
                        vals[s0] = f2bf(v.x);
                        vals[s1] = f2bf(v.y);
                    }
                }
                unsigned long long u0 = (unsigned long long)vals[0] | ((unsigned long long)vals[1] << 16)
                                      | ((unsigned long long)vals[2] << 32) | ((unsigned long long)vals[3] << 48);
                unsigned long long u1 = (unsigned long long)vals[4] | ((unsigned long long)vals[5] << 16)
                                      | ((unsigned long long)vals[6] << 32) | ((unsigned long long)vals[7] << 48);
                unsigned long long u2 = (unsigned long long)vals[8] | ((unsigned long long)vals[9] << 16)
                                      | ((unsigned long long)vals[10] << 32) | ((unsigned long long)vals[11] << 48);
                unsigned long long* op = (unsigned long long*)(Xsl + (size_t)(srow * 64 + w) * 16);
                op[0] = u0; op[1] = u1; op[2] = u2; op[3] = 0ull;
            }
        }
    }
    __syncthreads();

    int wcol[2][3];
    #pragma unroll
    for (int half = 0; half < 2; ++half)
        #pragma unroll
        for (int dx = 0; dx < 3; ++dx)
            wcol[half][dx] = ((half * 32 + ln + dx + 63) & 63) * 32 + kg * 16;

    float lsum = 0.0f;
    unsigned pk0[4][4];          // g=0 packed tanh pairs [i][pair]
    f32x16 acc[4];

    // ---- g=0 compute ----
    #pragma unroll
    for (int i = 0; i < 4; ++i) acc[i] = (f32x16){};
    #pragma unroll
    for (int dy = 0; dy < 3; ++dy) {
        #pragma unroll
        for (int dx = 0; dx < 3; ++dx) {
            const int tap = dy * 3 + dx;
            #pragma unroll
            for (int i = 0; i < 4; ++i) {
                const int nfl = wave * 8 + i;
                const int hl = nfl >> 1, half = nfl & 1;
                bf16x8 bb = *(const bf16x8*)((const char*)Xsl + (hl + dy) * 2048 + wcol[half][dx]);
                acc[i] = __builtin_amdgcn_mfma_f32_32x32x16_bf16(wreg[tap], bb, acc[i], 0, 0, 0);
            }
        }
    }
    // ---- g=0 tanh -> packed registers ----
    #pragma unroll
    for (int i = 0; i < 4; ++i) {
        const int nfl = wave * 8 + i;
        const int px = (R0 + (nfl >> 1)) * 64 + (nfl & 1) * 32 + ln;
        #pragma unroll
        for (int p = 0; p < 4; ++p) {
            const int co0 = 2 * (p & 1) + 8 * (p >> 1) + 4 * kg;
            if (co0 < 12) {
                float v0 = fmaf(acc[i][2 * p]     + cb[co0 * 4096 + px],       esc[co0],     ab[co0]);
                float v1 = fmaf(acc[i][2 * p + 1] + cb[(co0 + 1) * 4096 + px], esc[co0 + 1], ab[co0 + 1]);
                float t0 = fast_tanh_ld(v0, lsum);
                float t1 = fast_tanh_ld(v1, lsum);
                pk0[i][p] = (unsigned)f2bf(t0) | ((unsigned)f2bf(t1) << 16);
            }
        }
    }
    // ---- g=1 compute (acc reused) ----
    #pragma unroll
    for (int i = 0; i < 4; ++i) acc[i] = (f32x16){};
    #pragma unroll
    for (int dy = 0; dy < 3; ++dy) {
        #pragma unroll
        for (int dx = 0; dx < 3; ++dx) {
            const int tap = dy * 3 + dx;
            #pragma unroll
            for (int i = 0; i < 4; ++i) {
                const int nfl = wave * 8 + 4 + i;
                const int hl = nfl >> 1, half = nfl & 1;
                bf16x8 bb = *(const bf16x8*)((const char*)Xsl + (hl + dy) * 2048 + wcol[half][dx]);
                acc[i] = __builtin_amdgcn_mfma_f32_32x32x16_bf16(wreg[tap], bb, acc[i], 0, 0, 0);
            }
        }
    }

    __syncthreads();                 // all LDS reads done -> slice reusable
    // ---- scatter tanh results into LDS in X1 fragment layout ----
    #pragma unroll
    for (int g = 0; g < 2; ++g) {
        #pragma unroll
        for (int i = 0; i < 4; ++i) {
            const int nfl = wave * 8 + g * 4 + i;
            const int px = (R0 + (nfl >> 1)) * 64 + (nfl & 1) * 32 + ln;
            const int h = px >> 6, w = px & 63;
            const int q = (h & 1) ? ((w & 1) ? 1 : 3) : ((w & 1) ? 2 : 0);
            const int pxp_loc = ((h - R0) >> 1) * 32 + (w >> 1);    // [0,256)
            #pragma unroll
            for (int p = 0; p < 4; ++p) {
                const int co0 = 2 * (p & 1) + 8 * (p >> 1) + 4 * kg;
                if (co0 < 12) {
                    unsigned val;
                    if (g == 0) {
                        val = pk0[i][p];
                    } else {
                        float v0 = fmaf(acc[i][2 * p]     + cb[co0 * 4096 + px],       esc[co0],     ab[co0]);
                        float v1 = fmaf(acc[i][2 * p + 1] + cb[(co0 + 1) * 4096 + px], esc[co0 + 1], ab[co0 + 1]);
                        float t0 = fast_tanh_ld(v0, lsum);
                        float t1 = fast_tanh_ld(v1, lsum);
                        val = (unsigned)f2bf(t0) | ((unsigned)f2bf(t1) << 16);
                    }
                    const int ca = q * 12 + co0;                    // even
                    *(unsigned*)(lds + (size_t)((ca >> 3) * 2048 + pxp_loc * 8 + (ca & 7)) * 2) = val;
                }
            }
        }
    }
    __syncthreads();
    // ---- coalesced copy out: 1536 x 16B ----
    {
        const bf16x8* src = (const bf16x8*)lds;
        unsigned short* dstb = X1 + (size_t)b * 49152 + R0 * 128;
        #pragma unroll
        for (int i2 = 0; i2 < 6; ++i2) {
            const int idx = i2 * 256 + tid;
            const int chunk = idx >> 8, v = idx & 255;
            *(bf16x8*)(dstb + (size_t)chunk * 8192 + v * 8) = src[idx];
        }
    }
    lsum = wave_reduce_sum(lsum);
    if (lane == 0) red[wave] = lsum;
    __syncthreads();
    if (tid == 0) atomicAdd(&logacc[b], red[0] + red[1] + red[2] + red[3]);
}

// Layer 1. 4 blocks per batch (8 px-rows each), 256 threads = 4 waves
// (2 cog x 2 row-half). LDS: 10-row X1 slice (30.7 KB); W1 from global
// (L1/L2-hot). Epilogue staged through LDS for coalesced 16B stores.
__global__ __launch_bounds__(256, 4) void conv1_fused(
        const unsigned short* __restrict__ X1g, // (B,6,1024,8) bf16
        const unsigned short* __restrict__ W1,  // packed (9,2,3,2,32,8)
        const float* __restrict__ cb,           // (48,32,32)
        const float* __restrict__ ab,           // (48)
        const float* __restrict__ esc,          // exp(als1) (48)
        unsigned short* __restrict__ X2,        // (B,24,256,8) bf16
        float* __restrict__ logacc)             // (B)
{
    __shared__ __align__(16) char lds[30720];    // [6 chunk][10 slot][32 w] x16B
    __shared__ float red[4];

    const int tid = threadIdx.x;
    const int lane = tid & 63, wave = tid >> 6;
    const int ln = lane & 31, kg = lane >> 5;
    const int wm = wave >> 1;        // cog 0..1
    const int wq = wave & 1;         // row half
    const int blk = blockIdx.x;
    const int b = blk >> 2, R0 = (blk & 3) << 3;

    // ---- stage the 10-row slice (1920 x 16 B) ----
    {
        const unsigned short* xb = X1g + (size_t)b * 49152;
        #pragma unroll
        for (int rr = 0; rr < 8; ++rr) {
            const int idx = rr * 256 + tid;
            if (idx < 1920) {
                const int chunk = idx / 320;
                const int rem = idx - chunk * 320;
                const int slot = rem >> 5, w = rem & 31;
                const int hr = (R0 - 1 + slot + 32) & 31;
                bf16x8 v = *(const bf16x8*)(xb + (size_t)(chunk * 1024 + hr * 32 + w) * 8);
                *(bf16x8*)(lds + (size_t)(chunk * 320 + slot * 32 + w) * 16) = v;
            }
        }
    }
    __syncthreads();

    int wcolb[3];
    #pragma unroll
    for (int dx = 0; dx < 3; ++dx)
        wcolb[dx] = ((ln + dx + 31) & 31) * 16 + kg * 5120;

    const char* Wc = (const char*)W1 + wm * 3072 + (size_t)lane * 16;

    f32x16 acc[4];
    #pragma unroll
    for (int i = 0; i < 4; ++i) acc[i] = (f32x16){};

    #pragma unroll
    for (int kt = 0; kt < 3; ++kt) {
        #pragma unroll
        for (int dy = 0; dy < 3; ++dy) {
            #pragma unroll
            for (int dx = 0; dx < 3; ++dx) {
                const int tap = dy * 3 + dx;
                bf16x8 af = *(const bf16x8*)(Wc + tap * 6144 + kt * 1024);
                #pragma unroll
                for (int fi = 0; fi < 4; ++fi) {
                    bf16x8 bb = *(const bf16x8*)(lds + kt * 10240 + (wq * 4 + fi + dy) * 512 + wcolb[dx]);
                    acc[fi] = __builtin_amdgcn_mfma_f32_32x32x16_bf16(af, bb, acc[fi], 0, 0, 0);
                }
            }
        }
    }

    __syncthreads();                 // all LDS reads done -> slice reusable
    float lsum = 0.0f;
    // ---- tanh + scatter into LDS in X2 fragment layout ----
    #pragma unroll
    for (int fi = 0; fi < 4; ++fi) {
        const int h = R0 + wq * 4 + fi, w = ln;
        const int q = (h & 1) ? ((w & 1) ? 1 : 3) : ((w & 1) ? 2 : 0);
        const int pxp_loc = ((h - R0) >> 1) * 16 + (w >> 1);        // [0,64)
        #pragma unroll
        for (int p = 0; p < 8; ++p) {
            const int co0 = wm * 32 + 2 * (p & 1) + 8 * (p >> 1) + 4 * kg;
            if (co0 < 48) {                  // wm=1: uniform skip of p>=4
                float v0 = fmaf(acc[fi][2 * p]     + cb[co0 * 1024 + h * 32 + w],       esc[co0],     ab[co0]);
                float v1 = fmaf(acc[fi][2 * p + 1] + cb[(co0 + 1) * 1024 + h * 32 + w], esc[co0 + 1], ab[co0 + 1]);
                float t0 = fast_tanh_ld(v0, lsum);
                float t1 = fast_tanh_ld(v1, lsum);
                const int ci = q * 48 + co0;                        // even
                *(unsigned*)(lds + (size_t)((ci >> 3) * 512 + pxp_loc * 8 + (ci & 7)) * 2)
                    = (unsigned)f2bf(t0) | ((unsigned)f2bf(t1) << 16);
            }
        }
    }
    __syncthreads();
    // ---- coalesced copy out: 1536 x 16B (24 chunks x 1KB runs) ----
    {
        const bf16x8* src = (const bf16x8*)lds;
        unsigned short* dstb = X2 + (size_t)b * 49152 + R0 * 64;
        #pragma unroll
        for (int i2 = 0; i2 < 6; ++i2) {
            const int idx = i2 * 256 + tid;
            const int chunk = idx >> 6, v = idx & 63;
            *(bf16x8*)(dstb + (size_t)chunk * 2048 + v * 8) = src[idx];
        }
    }
    lsum = wave_reduce_sum(lsum);
    if (lane == 0) red[wave] = lsum;
    __syncthreads();
    if (tid == 0) atomicAdd(&logacc[b], red[0] + red[1] + red[2] + red[3]);
}

// Layer 2. One block per batch, 512 threads = 8 waves (2 cog-grp x 4 px-grp),
// 3x2 register tile per wave. X2 batch image (98304 B) fully in LDS; W2
// kt-slices (55296 B) streamed through a single LDS buffer with reg-staged
// prefetch (loads for kt+1 issued before computing kt; ds_write after barrier).
__global__ __launch_bounds__(512, 2) void conv2_mfma(
        const unsigned short* __restrict__ X2g, // (B,24,256,8) bf16
        const unsigned short* __restrict__ W2,  // packed (12 kt,9 tap,6 cog,64,8)
        const float* __restrict__ cb,           // (192,16,16)
        const float* __restrict__ ab,           // (192)
        const float* __restrict__ esc,          // exp(als2) (192)
        float* __restrict__ out)                // (B,192,256) fp32
{
    __shared__ __align__(16) char lds[153600];   // X2l 98304 + Wl 55296
    unsigned short* X2l = (unsigned short*)lds;
    unsigned short* Wl  = (unsigned short*)(lds + 98304);

    const int tid = threadIdx.x;
    const int lane = tid & 63, wave = tid >> 6;
    const int ln = lane & 31, kg = lane >> 5;
    const int wm = wave >> 2;        // 0..1: cog group (3 cogs each)
    const int wn = wave & 3;         // 0..3: px-frag group (2 frags each)
    const int b = blockIdx.x;

    // ---- stage X2 image (12 rounds) ----
    {
        const bf16x8* xs = (const bf16x8*)(X2g + (size_t)b * 49152);
        bf16x8* xd = (bf16x8*)X2l;
        bf16x8 t0[6];
        #pragma unroll
        for (int r = 0; r < 6; ++r) t0[r] = xs[tid + r * 512];
        #pragma unroll
        for (int r = 0; r < 6; ++r) xd[tid + r * 512] = t0[r];
        #pragma unroll
        for (int r = 0; r < 6; ++r) t0[r] = xs[tid + (6 + r) * 512];
        #pragma unroll
        for (int r = 0; r < 6; ++r) xd[tid + (6 + r) * 512] = t0[r];
    }
    // ---- stage W slice kt=0 ----
    bf16x8 sreg[7];
    {
        const bf16x8* ws = (const bf16x8*)W2;
        #pragma unroll
        for (int i = 0; i < 7; ++i)
            if (i < 6 || tid < 384) sreg[i] = ws[tid + i * 512];
        bf16x8* wd = (bf16x8*)Wl;
        #pragma unroll
        for (int i = 0; i < 7; ++i)
            if (i < 6 || tid < 384) wd[tid + i * 512] = sreg[i];
    }
    __syncthreads();

    int pxoff[2][9];
    #pragma unroll
    for (int t = 0; t < 2; ++t) {
        const int px = (wn * 2 + t) * 32 + ln;
        const int h = px >> 4, w = px & 15;
        #pragma unroll
        for (int dy = 0; dy < 3; ++dy) {
            const int hp = (h + dy + 15) & 15;
            #pragma unroll
            for (int dx = 0; dx < 3; ++dx) {
                const int wp = (w + dx + 15) & 15;
                pxoff[t][dy * 3 + dx] = (hp * 16 + wp) * 16;
            }
        }
    }
    const char* Xc = (const char*)X2l + kg * 4096;

    f32x16 acc[3][2];
    #pragma unroll
    for (int mi = 0; mi < 3; ++mi)
        #pragma unroll
        for (int ni = 0; ni < 2; ++ni)
            acc[mi][ni] = (f32x16){};

    for (int kt = 0; kt < 12; ++kt) {
        // issue next slice's global loads; they drain under this kt's MFMAs
        if (kt < 11) {
            const bf16x8* ws = (const bf16x8*)(W2 + (size_t)(kt + 1) * 27648);
            #pragma unroll
            for (int i = 0; i < 7; ++i)
                if (i < 6 || tid < 384) sreg[i] = ws[tid + i * 512];
        }

        const int xkb = kt * 8192;
        const char* Wcl = (const char*)Wl + wm * 3072 + (size_t)lane * 16;
        #pragma unroll
        for (int tap = 0; tap < 9; ++tap) {
            bf16x8 b0 = *(const bf16x8*)(Xc + pxoff[0][tap] + xkb);
            bf16x8 b1 = *(const bf16x8*)(Xc + pxoff[1][tap] + xkb);
            bf16x8 a0 = *(const bf16x8*)(Wcl + tap * 6144);
            bf16x8 a1 = *(const bf16x8*)(Wcl + tap * 6144 + 1024);
            bf16x8 a2 = *(const bf16x8*)(Wcl + tap * 6144 + 2048);
            acc[0][0] = __builtin_amdgcn_mfma_f32_32x32x16_bf16(a0, b0, acc[0][0], 0, 0, 0);
            acc[0][1] = __builtin_amdgcn_mfma_f32_32x32x16_bf16(a0, b1, acc[0][1], 0, 0, 0);
            acc[1][0] = __builtin_amdgcn_mfma_f32_32x32x16_bf16(a1, b0, acc[1][0], 0, 0, 0);
            acc[1][1] = __builtin_amdgcn_mfma_f32_32x32x16_bf16(a1, b1, acc[1][1], 0, 0, 0);
            acc[2][0] = __builtin_amdgcn_mfma_f32_32x32x16_bf16(a2, b0, acc[2][0], 0, 0, 0);
            acc[2][1] = __builtin_amdgcn_mfma_f32_32x32x16_bf16(a2, b1, acc[2][1], 0, 0, 0);
        }

        if (kt < 11) {
            __syncthreads();                    // all waves done reading Wl
            bf16x8* wd = (bf16x8*)Wl;
            #pragma unroll
            for (int i = 0; i < 7; ++i)
                if (i < 6 || tid < 384) wd[tid + i * 512] = sreg[i];
            __syncthreads();                    // Wl ready for kt+1
        }
    }

    #pragma unroll
    for (int mi = 0; mi < 3; ++mi) {
        const int cog = wm * 3 + mi;
        #pragma unroll
        for (int ni = 0; ni < 2; ++ni) {
            const int px = (wn * 2 + ni) * 32 + ln;
            #pragma unroll
            for (int r = 0; r < 16; ++r) {
                const int coe = cog * 32 + (r & 3) + 8 * (r >> 2) + 4 * kg;
                float v = fmaf(acc[mi][ni][r] + cb[coe * 256 + px], esc[coe], ab[coe]);
                out[((size_t)b * 192 + coe) * 256 + px] = v;
            }
        }
    }
}

__global__ __launch_bounds__(256) void finalize_kernel(const float* __restrict__ acc,
                                                       const float* __restrict__ consts,
                                                       float* __restrict__ out_ld) {
    int b = threadIdx.x;
    out_ld[b] = acc[b] + consts[0];
}

extern "C" void kernel_launch(void* const* d_in, const int* in_sizes, int n_in,
                              void* d_out, int out_size, void* d_ws, size_t ws_size,
                              hipStream_t stream) {
    const float* x    = (const float*)d_in[0];
    const float* K0   = (const float*)d_in[1];
    const float* cb0  = (const float*)d_in[2];
    const float* ab0  = (const float*)d_in[3];
    const float* als0 = (const float*)d_in[4];
    const float* K1   = (const float*)d_in[5];
    const float* cb1  = (const float*)d_in[6];
    const float* ab1  = (const float*)d_in[7];
    const float* als1 = (const float*)d_in[8];
    const float* K2   = (const float*)d_in[9];
    const float* cb2  = (const float*)d_in[10];
    const float* ab2  = (const float*)d_in[11];
    const float* als2 = (const float*)d_in[12];

    float* out_x  = (float*)d_out;        // (256,192,16,16)
    float* out_ld = out_x + 12582912;     // (256,)

    // ws layout (bytes). X2b lives at base (Xs is gone: squeeze fused into conv0).
    char* wsb = (char*)d_ws;
    unsigned short* X2b   = (unsigned short*)(wsb);                 // 25,165,824 B
    unsigned short* W1p   = (unsigned short*)(wsb + 25165824);      //     55,296 B
    unsigned short* W2p   = (unsigned short*)(wsb + 25221120);      //    663,552 B
    unsigned short* W0p   = (unsigned short*)(wsb + 25884672);      //      9,216 B
    float*          esc   = (float*)(wsb + 25893888);               //      1,008 B
    float*          ldacc = (float*)(wsb + 25894896);               //      1,024 B
    float*          consts= (float*)(wsb + 25895920);               //          4 B

    unsigned short* X1b = (unsigned short*)d_out;   // dead before conv2 writes

    init_kernel<<<1, 256, 0, stream>>>(ldacc, consts);
    logdet_const_kernel<<<155, 256, 0, stream>>>(K0, als0, K1, als1, K2, als2, consts);
    prep_weights<<<1296, 256, 0, stream>>>(K0, K1, K2, als0, als1, als2,
                                           W0p, W1p, W2p, esc);

    conv0_fused<<<dim3(1024), 256, 0, stream>>>(
        x, W0p, cb0, ab0, esc, X1b, ldacc);
    conv1_fused<<<dim3(1024), 256, 0, stream>>>(
        X1b, W1p, cb1, ab1, esc + 12, X2b, ldacc);
    conv2_mfma<<<dim3(BATCH), 512, 0, stream>>>(
        X2b, W2p, cb2, ab2, esc + 60, out_x);

    finalize_kernel<<<1, 256, 0, stream>>>(ldacc, consts, out_ld);
}

// Round 6
// 227.984 us; speedup vs baseline: 1.2323x; 1.2323x over previous
//
#include <hip/hip_runtime.h>
#include <math.h>

#define BATCH 256

typedef __attribute__((ext_vector_type(8))) short bf16x8;
typedef __attribute__((ext_vector_type(16))) float f32x16;

__device__ __forceinline__ float wave_reduce_sum(float v) {
    #pragma unroll
    for (int off = 32; off > 0; off >>= 1) v += __shfl_down(v, off, 64);
    return v;
}

__device__ __forceinline__ unsigned short f2bf(float f) {
    unsigned u = __float_as_uint(f);
    u += 0x7FFF + ((u >> 16) & 1);      // round-to-nearest-even
    return (unsigned short)(u >> 16);
}

// Fast tanh + log(1-tanh^2) from one exp:
//   u = e^(-2|v|); t = sgn(v)*(1-u)/(1+u); log(1-t^2) = log4 - 2|v| - 2*log(1+u)
__device__ __forceinline__ float fast_tanh_ld(float v, float& lsum) {
    float av = fabsf(v);
    float u = __expf(-2.0f * av);
    float onep = 1.0f + u;
    float rin = __builtin_amdgcn_rcpf(onep);
    lsum += 1.3862943611f - 2.0f * av - 2.0f * __logf(onep);
    return copysignf((1.0f - u) * rin, v);
}

__global__ __launch_bounds__(256) void init_kernel(float* acc, float* consts) {
    int t = threadIdx.x;
    acc[t] = 0.0f;
    if (t == 0) consts[0] = 0.0f;
}

// Parallel closed-form (Parseval) spectral logdet + actnorm logdet.
__global__ __launch_bounds__(256) void logdet_const_kernel(
        const float* __restrict__ K0, const float* __restrict__ als0,
        const float* __restrict__ K1, const float* __restrict__ als1,
        const float* __restrict__ K2, const float* __restrict__ als2,
        float* consts) {
    const int g = blockIdx.x * 256 + threadIdx.x;
    float val = 0.0f;
    if (g < 39312) {
        const float* K; int c, nn, ij;
        if (g < 144)       { K = K0; c = 12;  nn = 4096; ij = g; }
        else if (g < 2448) { K = K1; c = 48;  nn = 1024; ij = g - 144; }
        else               { K = K2; c = 192; nn = 256;  ij = g - 2448; }
        const int i = ij / c, j = ij - (ij / c) * c;
        const float* a  = K + (size_t)(i * c + j) * 9;
        const float* bp = K + (size_t)(j * c + i) * 9;
        float s = 0.0f;
        #pragma unroll
        for (int p = 0; p < 9; ++p) {
            const bool sub = (i == j) && (p == 4);
            float av = a[p]      - (sub ? 1.0f : 0.0f);
            float bv = bp[8 - p] - (sub ? 1.0f : 0.0f);
            s = fmaf(av, bv, s);
        }
        val = ((i == j) ? (a[4] - 1.0f) : 0.0f) - 0.5f * s;
        val *= (float)nn;
    } else if (g < 39564) {
        const int g2 = g - 39312;
        if (g2 < 12)      val = als0[g2] * 4096.0f;
        else if (g2 < 60) val = als1[g2 - 12] * 1024.0f;
        else              val = als2[g2 - 60] * 256.0f;
    }
    val = wave_reduce_sum(val);
    __shared__ float red[4];
    const int tid = threadIdx.x;
    if ((tid & 63) == 0) red[tid >> 6] = val;
    __syncthreads();
    if (tid == 0) atomicAdd(consts, red[0] + red[1] + red[2] + red[3]);
}

// Fragment-packed weights + prebaked exp(als) + prebaked affine CBE = cb*esc+ab
// (fp32, same layout as cb) so conv epilogues do fmaf(acc, esc, CBE) with CBE
// staged in LDS instead of 64 serialized global cb loads.
__global__ __launch_bounds__(256) void prep_weights(
        const float* __restrict__ K0, const float* __restrict__ K1,
        const float* __restrict__ K2,
        const float* __restrict__ als0, const float* __restrict__ als1,
        const float* __restrict__ als2,
        const float* __restrict__ cb0, const float* __restrict__ ab0,
        const float* __restrict__ cb1, const float* __restrict__ ab1,
        unsigned short* __restrict__ W0p, unsigned short* __restrict__ W1p,
        unsigned short* __restrict__ W2p, float* __restrict__ esc,
        float* __restrict__ CBE0, float* __restrict__ CBE1) {
    const int i = blockIdx.x * 256 + threadIdx.x;
    if (i < 252) {
        if (i < 12)      esc[i] = expf(als0[i]);
        else if (i < 60) esc[i] = expf(als1[i - 12]);
        else             esc[i] = expf(als2[i - 60]);
    }
    if (i < 49152) {               // CBE0: [12][4096]
        const int co = i >> 12;
        CBE0[i] = fmaf(cb0[i], expf(als0[co]), ab0[co]);
    }
    if (i < 49152) {               // CBE1: [48][1024]
        const int co = i >> 10;
        CBE1[i] = fmaf(cb1[i], expf(als1[co]), ab1[co]);
    }
    if (i < 4608) {                // 9 taps * 512
        int t = i;
        const int e  = t & 7;  t >>= 3;
        const int ln = t & 31; t >>= 5;
        const int kg = t & 1;  t >>= 1;
        const int tap = t;
        const int co = ln, ci = kg * 8 + e;
        W0p[i] = (co < 12 && ci < 12) ? f2bf(K0[((size_t)co * 12 + ci) * 9 + tap])
                                      : (unsigned short)0;
    }
    if (i < 27648) {               // 9 taps * 2 cog * 3 kt * 512
        int t = i;
        const int e  = t & 7;  t >>= 3;
        const int ln = t & 31; t >>= 5;
        const int kg = t & 1;  t >>= 1;
        const int kt = t % 3;  t /= 3;
        const int cog = t & 1; const int tap = t >> 1;
        const int co = cog * 32 + ln, ci = kt * 16 + kg * 8 + e;
        W1p[i] = (co < 48) ? f2bf(K1[((size_t)co * 48 + ci) * 9 + tap]) : (unsigned short)0;
    }
    if (i < 331776) {              // 12 kt * 9 tap * 6 cog * 64 lane * 8 e
        int t = i;
        const int e    = t & 7;  t >>= 3;
        const int lane = t & 63; t >>= 6;
        const int cog  = t % 6;  t /= 6;
        const int tap  = t % 9;  const int kt = t / 9;
        const int ln = lane & 31, kg = lane >> 5;
        const int co = cog * 32 + ln, ci = kt * 16 + kg * 8 + e;
        W2p[i] = f2bf(K2[((size_t)co * 192 + ci) * 9 + tap]);
    }
}

// Layer 0, fused squeeze + conv. 8 blocks per batch (8 px-rows each), 256
// threads = 4 waves, grid 2048 (= full-machine wave count). LDS: 10-row
// squeezed slice (20 KB) + CBE0 tile (24 KB) + esc -> 3 blocks/CU.
// W0 (9 KB, L2-hot) in registers. Epilogue: fmaf(acc, esc_lds, CBE_lds),
// pair-packed 4B scattered stores (L2 merges them; round-4 evidence).
__global__ __launch_bounds__(256, 3) void conv0_fused(
        const float* __restrict__ xin,          // (B,3,128,128) fp32
        const unsigned short* __restrict__ W0,  // packed (9,64,8)
        const float* __restrict__ CBE0,         // (12,64,64) = cb*esc+ab
        const float* __restrict__ esc,          // exp(als0) (12)
        unsigned short* __restrict__ X1,        // (B,6,1024,8) bf16
        float* __restrict__ logacc)             // (B)
{
    __shared__ __align__(16) char lds[45184];
    unsigned short* Xsl = (unsigned short*)lds;          // 10*64*32B = 20480
    float* CBEl = (float*)(lds + 20480);                 // 12*512*4  = 24576
    float* escl = (float*)(lds + 45056);                 // 12 floats
    float* red  = (float*)(lds + 45120);                 // 4 floats

    const int tid = threadIdx.x;
    const int lane = tid & 63, wave = tid >> 6;
    const int ln = lane & 31, kg = lane >> 5;
    const int blk = blockIdx.x;
    const int b = blk >> 3, R0 = (blk & 7) << 3;

    // ---- weights -> registers (9 frags) ----
    const char* Wc = (const char*)W0 + (size_t)lane * 16;
    bf16x8 wreg[9];
    #pragma unroll
    for (int tap = 0; tap < 9; ++tap)
        wreg[tap] = *(const bf16x8*)(Wc + tap * 1024);

    if (tid < 12) escl[tid] = esc[tid];

    // ---- fused squeeze of the 10-row slice (640 px) ----
    {
        const float* base = xin + (size_t)b * 49152;
        #pragma unroll
        for (int rr = 0; rr < 3; ++rr) {
            const int s = rr * 256 + tid;
            if (s < 640) {
                const int srow = s >> 6, w = s & 63;
                const int hr = (R0 - 1 + srow + 64) & 63;
                unsigned short vals[12];
                #pragma unroll
                for (int ci = 0; ci < 3; ++ci) {
                    #pragma unroll
                    for (int a = 0; a < 2; ++a) {
                        float2 v = *(const float2*)(base + ci * 16384 + (2 * hr + a) * 128 + 2 * w);
                        const int s0 = a ? 9 + ci : ci;
                        const int s1 = a ? 3 + ci : 6 + ci;
                        vals[s0] = f2bf(v.x);
                        vals[s1] = f2bf(v.y);
                    }
                }
                unsigned long long u0 = (unsigned long long)vals[0] | ((unsigned long long)vals[1] << 16)
                                      | ((unsigned long long)vals[2] << 32) | ((unsigned long long)vals[3] << 48);
                unsigned long long u1 = (unsigned long long)vals[4] | ((unsigned long long)vals[5] << 16)
                                      | ((unsigned long long)vals[6] << 32) | ((unsigned long long)vals[7] << 48);
                unsigned long long u2 = (unsigned long long)vals[8] | ((unsigned long long)vals[9] << 16)
                                      | ((unsigned long long)vals[10] << 32) | ((unsigned long long)vals[11] << 48);
                unsigned long long* op = (unsigned long long*)(Xsl + (size_t)(srow * 64 + w) * 16);
                op[0] = u0; op[1] = u1; op[2] = u2; op[3] = 0ull;
            }
        }
    }
    // ---- stage CBE0 tile [12][512] as float4 (coalesced) ----
    {
        const float4* src = (const float4*)(CBE0);       // [12][1024 f4]
        float4* dst = (float4*)CBEl;
        #pragma unroll
        for (int rr = 0; rr < 6; ++rr) {
            const int idx = rr * 256 + tid;              // [0,1536)
            const int co = idx >> 7, rem = idx & 127;    // 128 f4 per co-row
            dst[co * 128 + rem] = src[co * 1024 + (R0 << 4) + rem];
        }
    }
    __syncthreads();

    int wcol[2][3];
    #pragma unroll
    for (int half = 0; half < 2; ++half)
        #pragma unroll
        for (int dx = 0; dx < 3; ++dx)
            wcol[half][dx] = ((half * 32 + ln + dx + 63) & 63) * 32 + kg * 16;

    f32x16 acc[4];
    #pragma unroll
    for (int i = 0; i < 4; ++i) acc[i] = (f32x16){};

    #pragma unroll
    for (int dy = 0; dy < 3; ++dy) {
        #pragma unroll
        for (int dx = 0; dx < 3; ++dx) {
            const int tap = dy * 3 + dx;
            #pragma unroll
            for (int i = 0; i < 4; ++i) {
                const int nfl = wave * 4 + i;            // 0..15 local frag
                const int hl = nfl >> 1, half = nfl & 1;
                bf16x8 bb = *(const bf16x8*)((const char*)Xsl + (hl + dy) * 2048 + wcol[half][dx]);
                acc[i] = __builtin_amdgcn_mfma_f32_32x32x16_bf16(wreg[tap], bb, acc[i], 0, 0, 0);
            }
        }
    }

    float lsum = 0.0f;
    #pragma unroll
    for (int i = 0; i < 4; ++i) {
        const int nfl = wave * 4 + i;
        const int hl = nfl >> 1;
        const int h = R0 + hl, w = (nfl & 1) * 32 + ln;
        const int pl = hl * 64 + (nfl & 1) * 32 + ln;    // [0,512) local px
        const int q = (h & 1) ? ((w & 1) ? 1 : 3) : ((w & 1) ? 2 : 0);
        const int pxp = (h >> 1) * 32 + (w >> 1);
        #pragma unroll
        for (int p = 0; p < 4; ++p) {
            const int co0 = 2 * (p & 1) + 8 * (p >> 1) + 4 * kg;
            if (co0 < 12) {                  // kg=1: p=2,3 inactive (half-wave)
                float v0 = fmaf(acc[i][2 * p],     escl[co0],     CBEl[co0 * 512 + pl]);
                float v1 = fmaf(acc[i][2 * p + 1], escl[co0 + 1], CBEl[(co0 + 1) * 512 + pl]);
                float t0 = fast_tanh_ld(v0, lsum);
                float t1 = fast_tanh_ld(v1, lsum);
                const int ca = q * 12 + co0;             // even
                *(unsigned*)((char*)X1 + ((size_t)b * 49152 + ((ca >> 3) * 1024 + pxp) * 8 + (ca & 7)) * 2)
                    = (unsigned)f2bf(t0) | ((unsigned)f2bf(t1) << 16);
            }
        }
    }
    lsum = wave_reduce_sum(lsum);
    if (lane == 0) red[wave] = lsum;
    __syncthreads();
    if (tid == 0) atomicAdd(&logacc[b], red[0] + red[1] + red[2] + red[3]);
}

// Layer 1. 8 blocks per batch (4 px-rows each), 256 threads = 4 waves
// (2 cog x 2 row-half), grid 2048. LDS: 6-row X1 slice (18 KB) + CBE1 tile
// (24 KB) -> 3 blocks/CU. W1 fragments batch-loaded into registers per kt
// (MLP 9). Pair-packed 4B scattered stores.
__global__ __launch_bounds__(256, 3) void conv1_fused(
        const unsigned short* __restrict__ X1g, // (B,6,1024,8) bf16
        const unsigned short* __restrict__ W1,  // packed (9,2,3,2,32,8)
        const float* __restrict__ CBE1,         // (48,32,32) = cb*esc+ab
        const float* __restrict__ esc,          // exp(als1) (48)
        unsigned short* __restrict__ X2,        // (B,24,256,8) bf16
        float* __restrict__ logacc)             // (B)
{
    __shared__ __align__(16) char lds[43264];
    // slice: [6 chunk][6 slot][32 w] x 16B = 18432
    float* CBEl = (float*)(lds + 18432);                 // 48*128*4 = 24576
    float* escl = (float*)(lds + 43008);                 // 48 floats
    float* red  = (float*)(lds + 43200);                 // 4 floats

    const int tid = threadIdx.x;
    const int lane = tid & 63, wave = tid >> 6;
    const int ln = lane & 31, kg = lane >> 5;
    const int wm = wave >> 1;        // cog 0..1
    const int wq = wave & 1;         // row half (2 rows each)
    const int blk = blockIdx.x;
    const int b = blk >> 3, R0 = (blk & 7) << 2;

    if (tid < 48) escl[tid] = esc[tid];

    // ---- stage the 6-row slice (1152 x 16 B) ----
    {
        const unsigned short* xb = X1g + (size_t)b * 49152;
        #pragma unroll
        for (int rr = 0; rr < 5; ++rr) {
            const int idx = rr * 256 + tid;
            if (idx < 1152) {
                const int chunk = idx / 192;
                const int rem = idx - chunk * 192;
                const int slot = rem >> 5, w = rem & 31;
                const int hr = (R0 - 1 + slot + 32) & 31;
                bf16x8 v = *(const bf16x8*)(xb + (size_t)(chunk * 1024 + hr * 32 + w) * 8);
                *(bf16x8*)(lds + (size_t)(chunk * 192 + slot * 32 + w) * 16) = v;
            }
        }
    }
    // ---- stage CBE1 tile [48][128] as float4 (coalesced) ----
    {
        const float4* src = (const float4*)(CBE1);       // [48][256 f4]
        float4* dst = (float4*)CBEl;
        #pragma unroll
        for (int rr = 0; rr < 6; ++rr) {
            const int idx = rr * 256 + tid;              // [0,1536)
            const int co = idx >> 5, rem = idx & 31;     // 32 f4 per co-row
            dst[co * 32 + rem] = src[co * 256 + (R0 << 3) + rem];
        }
    }
    __syncthreads();

    int wcolb[3];
    #pragma unroll
    for (int dx = 0; dx < 3; ++dx)
        wcolb[dx] = ((ln + dx + 31) & 31) * 16;

    const char* Wc = (const char*)W1 + wm * 3072 + (size_t)lane * 16;

    f32x16 acc[2];
    #pragma unroll
    for (int i = 0; i < 2; ++i) acc[i] = (f32x16){};

    #pragma unroll
    for (int kt = 0; kt < 3; ++kt) {
        bf16x8 wk[9];                    // batch all 9 tap frags: MLP 9
        #pragma unroll
        for (int tap = 0; tap < 9; ++tap)
            wk[tap] = *(const bf16x8*)(Wc + tap * 6144 + kt * 1024);
        const char* sb = lds + (2 * kt + kg) * 3072;
        #pragma unroll
        for (int dy = 0; dy < 3; ++dy) {
            #pragma unroll
            for (int dx = 0; dx < 3; ++dx) {
                const int tap = dy * 3 + dx;
                #pragma unroll
                for (int fi = 0; fi < 2; ++fi) {
                    bf16x8 bb = *(const bf16x8*)(sb + (wq * 2 + fi + dy) * 512 + wcolb[dx]);
                    acc[fi] = __builtin_amdgcn_mfma_f32_32x32x16_bf16(wk[tap], bb, acc[fi], 0, 0, 0);
                }
            }
        }
    }

    float lsum = 0.0f;
    #pragma unroll
    for (int fi = 0; fi < 2; ++fi) {
        const int h = R0 + wq * 2 + fi, w = ln;
        const int pl = (wq * 2 + fi) * 32 + w;           // [0,128) local px
        const int q = (h & 1) ? ((w & 1) ? 1 : 3) : ((w & 1) ? 2 : 0);
        const int pxp = (h >> 1) * 16 + (w >> 1);
        #pragma unroll
        for (int p = 0; p < 8; ++p) {
            const int co0 = wm * 32 + 2 * (p & 1) + 8 * (p >> 1) + 4 * kg;
            if (co0 < 48) {                  // wm=1: uniform skip of p>=4
                float v0 = fmaf(acc[fi][2 * p],     escl[co0],     CBEl[co0 * 128 + pl]);
                float v1 = fmaf(acc[fi][2 * p + 1], escl[co0 + 1], CBEl[(co0 + 1) * 128 + pl]);
                float t0 = fast_tanh_ld(v0, lsum);
                float t1 = fast_tanh_ld(v1, lsum);
                const int ci = q * 48 + co0;             // even
                *(unsigned*)((char*)X2 + ((size_t)b * 49152 + ((ci >> 3) * 256 + pxp) * 8 + (ci & 7)) * 2)
                    = (unsigned)f2bf(t0) | ((unsigned)f2bf(t1) << 16);
            }
        }
    }
    lsum = wave_reduce_sum(lsum);
    if (lane == 0) red[wave] = lsum;
    __syncthreads();
    if (tid == 0) atomicAdd(&logacc[b], red[0] + red[1] + red[2] + red[3]);
}

// Layer 2. One block per batch, 512 threads = 8 waves (2 cog-grp x 4 px-grp),
// 3x2 register tile per wave. X2 batch image (98304 B) fully in LDS; W2
// kt-slices (55296 B) streamed through a single LDS buffer with reg-staged
// prefetch (loads for kt+1 issued before computing kt; ds_write after barrier).
__global__ __launch_bounds__(512, 2) void conv2_mfma(
        const unsigned short* __restrict__ X2g, // (B,24,256,8) bf16
        const unsigned short* __restrict__ W2,  // packed (12 kt,9 tap,6 cog,64,8)
        const float* __restrict__ cb,           // (192,16,16)
        const float* __restrict__ ab,           // (192)
        const float* __restrict__ esc,          // exp(als2) (192)
        float* __restrict__ out)                // (B,192,256) fp32
{
    __shared__ __align__(16) char lds[153600];   // X2l 98304 + Wl 55296
    unsigned short* X2l = (unsigned short*)lds;
    unsigned short* Wl  = (unsigned short*)(lds + 98304);

    const int tid = threadIdx.x;
    const int lane = tid & 63, wave = tid >> 6;
    const int ln = lane & 31, kg = lane >> 5;
    const int wm = wave >> 2;        // 0..1: cog group (3 cogs each)
    const int wn = wave & 3;         // 0..3: px-frag group (2 frags each)
    const int b = blockIdx.x;

    // ---- stage X2 image (12 rounds) ----
    {
        const bf16x8* xs = (const bf16x8*)(X2g + (size_t)b * 49152);
        bf16x8* xd = (bf16x8*)X2l;
        bf16x8 t0[6];
        #pragma unroll
        for (int r = 0; r < 6; ++r) t0[r] = xs[tid + r * 512];
        #pragma unroll
        for (int r = 0; r < 6; ++r) xd[tid + r * 512] = t0[r];
        #pragma unroll
        for (int r = 0; r < 6; ++r) t0[r] = xs[tid + (6 + r) * 512];
        #pragma unroll
        for (int r = 0; r < 6; ++r) xd[tid + (6 + r) * 512] = t0[r];
    }
    // ---- stage W slice kt=0 ----
    bf16x8 sreg[7];
    {
        const bf16x8* ws = (const bf16x8*)W2;
        #pragma unroll
        for (int i = 0; i < 7; ++i)
            if (i < 6 || tid < 384) sreg[i] = ws[tid + i * 512];
        bf16x8* wd = (bf16x8*)Wl;
        #pragma unroll
        for (int i = 0; i < 7; ++i)
            if (i < 6 || tid < 384) wd[tid + i * 512] = sreg[i];
    }
    __syncthreads();

    int pxoff[2][9];
    #pragma unroll
    for (int t = 0; t < 2; ++t) {
        const int px = (wn * 2 + t) * 32 + ln;
        const int h = px >> 4, w = px & 15;
        #pragma unroll
        for (int dy = 0; dy < 3; ++dy) {
            const int hp = (h + dy + 15) & 15;
            #pragma unroll
            for (int dx = 0; dx < 3; ++dx) {
                const int wp = (w + dx + 15) & 15;
                pxoff[t][dy * 3 + dx] = (hp * 16 + wp) * 16;
            }
        }
    }
    const char* Xc = (const char*)X2l + kg * 4096;

    f32x16 acc[3][2];
    #pragma unroll
    for (int mi = 0; mi < 3; ++mi)
        #pragma unroll
        for (int ni = 0; ni < 2; ++ni)
            acc[mi][ni] = (f32x16){};

    for (int kt = 0; kt < 12; ++kt) {
        // issue next slice's global loads; they drain under this kt's MFMAs
        if (kt < 11) {
            const bf16x8* ws = (const bf16x8*)(W2 + (size_t)(kt + 1) * 27648);
            #pragma unroll
            for (int i = 0; i < 7; ++i)
                if (i < 6 || tid < 384) sreg[i] = ws[tid + i * 512];
        }

        const int xkb = kt * 8192;
        const char* Wcl = (const char*)Wl + wm * 3072 + (size_t)lane * 16;
        #pragma unroll
        for (int tap = 0; tap < 9; ++tap) {
            bf16x8 b0 = *(const bf16x8*)(Xc + pxoff[0][tap] + xkb);
            bf16x8 b1 = *(const bf16x8*)(Xc + pxoff[1][tap] + xkb);
            bf16x8 a0 = *(const bf16x8*)(Wcl + tap * 6144);
            bf16x8 a1 = *(const bf16x8*)(Wcl + tap * 6144 + 1024);
            bf16x8 a2 = *(const bf16x8*)(Wcl + tap * 6144 + 2048);
            acc[0][0] = __builtin_amdgcn_mfma_f32_32x32x16_bf16(a0, b0, acc[0][0], 0, 0, 0);
            acc[0][1] = __builtin_amdgcn_mfma_f32_32x32x16_bf16(a0, b1, acc[0][1], 0, 0, 0);
            acc[1][0] = __builtin_amdgcn_mfma_f32_32x32x16_bf16(a1, b0, acc[1][0], 0, 0, 0);
            acc[1][1] = __builtin_amdgcn_mfma_f32_32x32x16_bf16(a1, b1, acc[1][1], 0, 0, 0);
            acc[2][0] = __builtin_amdgcn_mfma_f32_32x32x16_bf16(a2, b0, acc[2][0], 0, 0, 0);
            acc[2][1] = __builtin_amdgcn_mfma_f32_32x32x16_bf16(a2, b1, acc[2][1], 0, 0, 0);
        }

        if (kt < 11) {
            __syncthreads();                    // all waves done reading Wl
            bf16x8* wd = (bf16x8*)Wl;
            #pragma unroll
            for (int i = 0; i < 7; ++i)
                if (i < 6 || tid < 384) wd[tid + i * 512] = sreg[i];
            __syncthreads();                    // Wl ready for kt+1
        }
    }

    #pragma unroll
    for (int mi = 0; mi < 3; ++mi) {
        const int cog = wm * 3 + mi;
        #pragma unroll
        for (int ni = 0; ni < 2; ++ni) {
            const int px = (wn * 2 + ni) * 32 + ln;
            #pragma unroll
            for (int r = 0; r < 16; ++r) {
                const int coe = cog * 32 + (r & 3) + 8 * (r >> 2) + 4 * kg;
                float v = fmaf(acc[mi][ni][r] + cb[coe * 256 + px], esc[coe], ab[coe]);
                out[((size_t)b * 192 + coe) * 256 + px] = v;
            }
        }
    }
}

__global__ __launch_bounds__(256) void finalize_kernel(const float* __restrict__ acc,
                                                       const float* __restrict__ consts,
                                                       float* __restrict__ out_ld) {
    int b = threadIdx.x;
    out_ld[b] = acc[b] + consts[0];
}

extern "C" void kernel_launch(void* const* d_in, const int* in_sizes, int n_in,
                              void* d_out, int out_size, void* d_ws, size_t ws_size,
                              hipStream_t stream) {
    const float* x    = (const float*)d_in[0];
    const float* K0   = (const float*)d_in[1];
    const float* cb0  = (const float*)d_in[2];
    const float* ab0  = (const float*)d_in[3];
    const float* als0 = (const float*)d_in[4];
    const float* K1   = (const float*)d_in[5];
    const float* cb1  = (const float*)d_in[6];
    const float* ab1  = (const float*)d_in[7];
    const float* als1 = (const float*)d_in[8];
    const float* K2   = (const float*)d_in[9];
    const float* cb2  = (const float*)d_in[10];
    const float* ab2  = (const float*)d_in[11];
    const float* als2 = (const float*)d_in[12];

    float* out_x  = (float*)d_out;        // (256,192,16,16)
    float* out_ld = out_x + 12582912;     // (256,)

    // ws layout (bytes).
    char* wsb = (char*)d_ws;
    unsigned short* X2b   = (unsigned short*)(wsb);                 // 25,165,824 B
    unsigned short* W1p   = (unsigned short*)(wsb + 25165824);      //     55,296 B
    unsigned short* W2p   = (unsigned short*)(wsb + 25221120);      //    663,552 B
    unsigned short* W0p   = (unsigned short*)(wsb + 25884672);      //      9,216 B
    float*          esc   = (float*)(wsb + 25893888);               //      1,008 B
    float*          ldacc = (float*)(wsb + 25894896);               //      1,024 B
    float*          consts= (float*)(wsb + 25895920);               //          4 B

    // d_out scratch: X1 in [0, 25165824); CBE0/CBE1 in the free tail —
    // all dead before conv2 overwrites d_out with the real output.
    unsigned short* X1b  = (unsigned short*)d_out;
    float*          CBE0 = (float*)((char*)d_out + 25165824);       //    196,608 B
    float*          CBE1 = (float*)((char*)d_out + 25362432);       //    196,608 B

    init_kernel<<<1, 256, 0, stream>>>(ldacc, consts);
    logdet_const_kernel<<<155, 256, 0, stream>>>(K0, als0, K1, als1, K2, als2, consts);
    prep_weights<<<1296, 256, 0, stream>>>(K0, K1, K2, als0, als1, als2,
                                           cb0, ab0, cb1, ab1,
                                           W0p, W1p, W2p, esc, CBE0, CBE1);

    conv0_fused<<<dim3(2048), 256, 0, stream>>>(
        x, W0p, CBE0, esc, X1b, ldacc);
    conv1_fused<<<dim3(2048), 256, 0, stream>>>(
        X1b, W1p, CBE1, esc + 12, X2b, ldacc);
    conv2_mfma<<<dim3(BATCH), 512, 0, stream>>>(
        X2b, W2p, cb2, ab2, esc + 60, out_x);

    finalize_kernel<<<1, 256, 0, stream>>>(ldacc, consts, out_ld);
}